// Round 2
// baseline (294.529 us; speedup 1.0000x reference)
//
#include <hip/hip_runtime.h>
#include <hip/hip_bf16.h>
#include <stdint.h>

#define BATCH   16384
#define D_IN    2000
#define HID     100
#define OUT_DIM 2
#define BN_EPS_VAL 1e-5f

#define BK      32
#define BN_PAD  128
#define KT      63                      // ceil(2000/32)
#define W1Q_ELEMS (KT * BN_PAD * BK)    // 258048

typedef float f32x4 __attribute__((ext_vector_type(4)));
typedef short bf16x8 __attribute__((ext_vector_type(8)));

// ---------------- workspace layout (bytes) ----------------
// [0, 4096): float F[] scalars & small arrays (zeroed by memset each launch)
//   F[0] absmax_sig  F[1] absmax_W1  F[2] absmax_W2  F[3] absmax_h1  F[4] absmax_o2
//   F[16..116)  b1_int[100]
//   F[116..316) w2_int[2][100]
//   F[320..420) mu[100]      F[420..520) rstd[100]
//   u32 S1[100] at F+520     u32 S2[100] at F+620
//   F[920..922) b2_int[2]    F[922] b_s2
// [4096, +516096): ushort w1q[63][128][32]   (bf16 bits, K-tile-major)
// [1MB, +6553600): float h1[16384][100]
// [8MB, +1638400): u8 q2[16384][100]
// [10MB, +131072): float out2[16384][2]
#define WS_W1Q_OFF 4096
#define WS_H1_OFF  (1u << 20)
#define WS_Q2_OFF  (8u << 20)
#define WS_O2_OFF  (10u << 20)

__device__ __forceinline__ void block_atomic_maxf(float v, float* dst) {
#pragma unroll
    for (int off = 32; off > 0; off >>= 1)
        v = fmaxf(v, __shfl_xor(v, off, 64));
    __shared__ float sm[8];
    const int w = threadIdx.x >> 6;
    if ((threadIdx.x & 63) == 0) sm[w] = v;
    __syncthreads();
    if (threadIdx.x == 0) {
        const int nw = (blockDim.x + 63) >> 6;
        float m = sm[0];
        for (int i = 1; i < nw; ++i) m = fmaxf(m, sm[i]);
        atomicMax((unsigned int*)dst, __float_as_uint(m)); // all values >= 0
    }
}

// ---------------- K0: absmax of sig / W1 / W2 ----------------
__global__ __launch_bounds__(256)
void k_absmax(const float* __restrict__ sig, const float* __restrict__ W1,
              const float* __restrict__ W2, float* __restrict__ F) {
    float m = 0.0f;
    const int b = blockIdx.x;
    if (b < 2048) {
        const float4* p = (const float4*)sig;
        const int n4 = BATCH * D_IN / 4;
        for (int i = b * 256 + threadIdx.x; i < n4; i += 2048 * 256) {
            float4 v = p[i];
            m = fmaxf(m, fmaxf(fmaxf(fabsf(v.x), fabsf(v.y)),
                               fmaxf(fabsf(v.z), fabsf(v.w))));
        }
        block_atomic_maxf(m, &F[0]);
    } else if (b < 2064) {
        const float4* p = (const float4*)W1;
        const int n4 = HID * D_IN / 4;
        for (int i = (b - 2048) * 256 + threadIdx.x; i < n4; i += 16 * 256) {
            float4 v = p[i];
            m = fmaxf(m, fmaxf(fmaxf(fabsf(v.x), fabsf(v.y)),
                               fmaxf(fabsf(v.z), fabsf(v.w))));
        }
        block_atomic_maxf(m, &F[1]);
    } else {
        if (threadIdx.x < OUT_DIM * HID) m = fabsf(W2[threadIdx.x]);
        block_atomic_maxf(m, &F[2]);
    }
}

// ---------------- K1: quantize W1 (tiled bf16), b1, W2 ----------------
__global__ __launch_bounds__(256)
void k_prep(const float* __restrict__ W1, const float* __restrict__ b1,
            const float* __restrict__ W2, float* __restrict__ F,
            unsigned short* __restrict__ w1q) {
    const int tid = blockIdx.x * 256 + threadIdx.x;
    const float ws1 = F[1];
    if (tid < W1Q_ELEMS) {
        const int kt = tid >> 12;        // / (128*32)
        const int r  = tid & 4095;
        const int n  = r >> 5;
        const int kk = r & 31;
        const int k  = kt * 32 + kk;
        float q = 0.0f;
        if (n < HID && k < D_IN) {
            q = rintf(W1[n * D_IN + k] / ws1);
            q = fminf(fmaxf(q, -2.0f), 1.0f);
        }
        w1q[tid] = (unsigned short)(__float_as_uint(q) >> 16); // exact bf16 (small ints)
    } else if (tid < W1Q_ELEMS + HID) {
        const int h = tid - W1Q_ELEMS;
        const float s1 = F[0] / 15.0f;
        const float bs = ws1 * s1;
        F[16 + h] = fminf(fmaxf(rintf(b1[h] / bs), -2.0f), 1.0f);
    } else if (tid < W1Q_ELEMS + HID + OUT_DIM * HID) {
        const int j = tid - (W1Q_ELEMS + HID);
        const float ws2 = F[2];
        F[116 + j] = fminf(fmaxf(rintf(W2[j] / ws2), -2.0f), 1.0f);
    }
}

// ---------------- K2: GEMM1 (MFMA bf16) + bias + relu + absmax(h1) ----------------
// tile: 32 rows x 128 cols (HID padded), K step 32. 4 waves:
//   wid&1 -> row half (16 rows), wid>>1 -> n-tile group of 4 (16 cols each)
__global__ __launch_bounds__(256)
void k_gemm1(const float* __restrict__ sig, const unsigned short* __restrict__ w1q,
             float* __restrict__ F, float* __restrict__ h1) {
    __shared__ unsigned short As[32][40];   // stride 40 elems = 80 B (2-way bank alias, free)
    __shared__ unsigned short Bs[128][40];
    const int tid  = threadIdx.x;
    const int lane = tid & 63;
    const int wid  = tid >> 6;
    const float s1  = F[0] / 15.0f;
    const float bs1 = F[1] * s1;
    const int m0 = blockIdx.x * 32;

    // A staging: thread -> (row = tid>>3, 4 consecutive k at (tid&7)*4)
    const int ar  = tid >> 3;
    const int akl = (tid & 7) * 4;
    const float* aptr = sig + (size_t)(m0 + ar) * D_IN + akl;

    // compute-phase indices
    const int rh = (wid & 1) * 16;
    const int ng = (wid >> 1) * 4;
    const int fr = lane & 15;
    const int fk = (lane >> 4) * 8;

    f32x4 acc[4] = {};

    for (int kt = 0; kt < KT; ++kt) {
        const int kbase = kt * BK;
        // ---- stage A (quantize sig -> bf16 int codes) ----
        float4 v;
        if (kbase + akl < D_IN) v = *(const float4*)(aptr + kbase);
        else                    v = make_float4(0.f, 0.f, 0.f, 0.f);
        ushort4 qa;
        {
            float q;
            q = fminf(fmaxf(rintf(v.x / s1), -16.f), 15.f); qa.x = (unsigned short)(__float_as_uint(q) >> 16);
            q = fminf(fmaxf(rintf(v.y / s1), -16.f), 15.f); qa.y = (unsigned short)(__float_as_uint(q) >> 16);
            q = fminf(fmaxf(rintf(v.z / s1), -16.f), 15.f); qa.z = (unsigned short)(__float_as_uint(q) >> 16);
            q = fminf(fmaxf(rintf(v.w / s1), -16.f), 15.f); qa.w = (unsigned short)(__float_as_uint(q) >> 16);
        }
        *(ushort4*)&As[ar][akl] = qa;
        // ---- stage B (pre-tiled w1q: contiguous 8 KB per K-tile) ----
        {
            const uint4* bt = (const uint4*)(w1q + (size_t)kt * (BN_PAD * BK));
            uint4 b0 = bt[tid];
            uint4 b1v = bt[tid + 256];
            *(uint4*)&Bs[tid >> 2][(tid & 3) * 8] = b0;
            *(uint4*)&Bs[(tid + 256) >> 2][(tid & 3) * 8] = b1v;
        }
        __syncthreads();
        // ---- MFMA ----
        bf16x8 a = *(const bf16x8*)&As[rh + fr][fk];
#pragma unroll
        for (int t = 0; t < 4; ++t) {
            bf16x8 b = *(const bf16x8*)&Bs[(ng + t) * 16 + fr][fk];
            acc[t] = __builtin_amdgcn_mfma_f32_16x16x32_bf16(a, b, acc[t], 0, 0, 0);
        }
        __syncthreads();
    }

    // epilogue: h = relu((acc + b1_int) * bs1); store + absmax
    float lmax = 0.0f;
#pragma unroll
    for (int t = 0; t < 4; ++t) {
        const int n = (ng + t) * 16 + fr;               // C/D: col = lane&15
        if (n < HID) {
            const float bi = F[16 + n];
#pragma unroll
            for (int r = 0; r < 4; ++r) {
                const int m = m0 + rh + (lane >> 4) * 4 + r;  // C/D: row = (lane>>4)*4+reg
                float h = (acc[t][r] + bi) * bs1;
                h = fmaxf(h, 0.0f);
                h1[(size_t)m * HID + n] = h;
                lmax = fmaxf(lmax, h);
            }
        }
    }
    block_atomic_maxf(lmax, &F[3]);
}

// ---------------- K3: quantize h1 -> int8 codes + exact column sums ----------------
__global__ __launch_bounds__(256)
void k_quant_h(const float* __restrict__ h1, unsigned char* __restrict__ q2,
               const float* __restrict__ F, unsigned int* __restrict__ S1,
               unsigned int* __restrict__ S2) {
    __shared__ unsigned int ls1[HID], ls2[HID];
    if (threadIdx.x < HID) { ls1[threadIdx.x] = 0u; ls2[threadIdx.x] = 0u; }
    __syncthreads();
    const float s2 = F[3] / 127.0f;
    const int base = blockIdx.x * 6400;          // 64 rows x 100 cols
#pragma unroll 5
    for (int it = 0; it < 25; ++it) {
        const int idx = base + it * 256 + threadIdx.x;
        const float h = h1[idx];                 // >= 0
        const int q = (int)fminf(rintf(h / s2), 127.0f);
        q2[idx] = (unsigned char)q;
        const int c = idx % HID;
        atomicAdd(&ls1[c], (unsigned int)q);
        atomicAdd(&ls2[c], (unsigned int)(q * q));
    }
    __syncthreads();
    if (threadIdx.x < HID) {
        atomicAdd(&S1[threadIdx.x], ls1[threadIdx.x]);
        atomicAdd(&S2[threadIdx.x], ls2[threadIdx.x]);
    }
}

// ---------------- K4: BN stats (exact integer sums -> double) + b2 quant ----------------
__global__ void k_bnprep(const float* __restrict__ b2, float* __restrict__ F,
                         const unsigned int* __restrict__ S1,
                         const unsigned int* __restrict__ S2) {
    const int t = threadIdx.x;
    const float s2  = F[3] / 127.0f;
    const float ws2 = F[2];
    const float bs2 = ws2 * s2;
    if (t < HID) {
        const double sd   = (double)s2;
        const double mean = sd * ((double)S1[t] / 16384.0);
        const double ex2  = sd * sd * ((double)S2[t] / 16384.0);
        const double var  = ex2 - mean * mean;
        const float varf  = (float)var;
        const float vpe   = varf + BN_EPS_VAL;
        const float rf    = (float)(1.0 / sqrt((double)vpe));
        F[320 + t] = (float)mean;
        F[420 + t] = rf;
    }
    if (t < OUT_DIM) F[920 + t] = fminf(fmaxf(rintf(b2[t] / bs2), -2.0f), 1.0f);
    if (t == 64) F[922] = bs2;
}

// ---------------- K5: BN + GEMM2 (N=2, VALU) + relu + absmax ----------------
__global__ __launch_bounds__(256)
void k_gemm2(const unsigned char* __restrict__ q2, float* __restrict__ F,
             const float* __restrict__ gamma, const float* __restrict__ beta,
             float* __restrict__ out2) {
    __shared__ float sw[2 * HID], smu[HID], sr[HID], sg[HID], sb[HID];
    __shared__ float ssc[4];
    const int t = threadIdx.x;
    if (t < 2 * HID) sw[t] = F[116 + t];
    if (t < HID) { smu[t] = F[320 + t]; sr[t] = F[420 + t]; sg[t] = gamma[t]; sb[t] = beta[t]; }
    if (t == 200) ssc[0] = F[3] / 127.0f;  // s2
    if (t == 201) ssc[1] = F[922];         // b_s2
    if (t == 202) ssc[2] = F[920];         // b2_int[0]
    if (t == 203) ssc[3] = F[921];         // b2_int[1]
    __syncthreads();
    const int row = blockIdx.x * 256 + t;
    const unsigned int* rp = (const unsigned int*)(q2 + (size_t)row * HID);
    const float s2 = ssc[0];
    float a0 = 0.0f, a1 = 0.0f;
#pragma unroll
    for (int j = 0; j < 25; ++j) {
        const unsigned int u = rp[j];
#pragma unroll
        for (int bb = 0; bb < 4; ++bb) {
            const int h = j * 4 + bb;
            const float q = (float)((u >> (8 * bb)) & 255u);
            const float x2v = q * s2;                            // dequant (matches ref)
            const float xb  = fmaf((x2v - smu[h]) * sr[h], sg[h], sb[h]); // BN
            const float xi  = xb / s2;                           // x_int (true division)
            a0 = fmaf(xi, sw[h], a0);
            a1 = fmaf(xi, sw[HID + h], a1);
        }
    }
    const float o0 = fmaxf((a0 + ssc[2]) * ssc[1], 0.0f);
    const float o1 = fmaxf((a1 + ssc[3]) * ssc[1], 0.0f);
    out2[row * 2 + 0] = o0;
    out2[row * 2 + 1] = o1;
    block_atomic_maxf(fmaxf(o0, o1), &F[4]);
}

// ---------------- K6: final 8-bit quant_act ----------------
__global__ __launch_bounds__(256)
void k_final(const float* __restrict__ out2, const float* __restrict__ F,
             float* __restrict__ out) {
    const int i = blockIdx.x * 256 + threadIdx.x;     // 8192 float4s
    const float s3 = F[4] / 127.0f;
    float4 v = ((const float4*)out2)[i];
    float4 r;
    r.x = fminf(fmaxf(rintf(v.x / s3), -128.f), 127.f) * s3;
    r.y = fminf(fmaxf(rintf(v.y / s3), -128.f), 127.f) * s3;
    r.z = fminf(fmaxf(rintf(v.z / s3), -128.f), 127.f) * s3;
    r.w = fminf(fmaxf(rintf(v.w / s3), -128.f), 127.f) * s3;
    ((float4*)out)[i] = r;
}

extern "C" void kernel_launch(void* const* d_in, const int* in_sizes, int n_in,
                              void* d_out, int out_size, void* d_ws, size_t ws_size,
                              hipStream_t stream) {
    const float* sig   = (const float*)d_in[0];
    const float* W1    = (const float*)d_in[1];
    const float* b1    = (const float*)d_in[2];
    const float* W2    = (const float*)d_in[3];
    const float* b2    = (const float*)d_in[4];
    const float* gamma = (const float*)d_in[5];
    const float* beta  = (const float*)d_in[6];

    float* F = (float*)d_ws;
    unsigned short* w1q = (unsigned short*)((char*)d_ws + WS_W1Q_OFF);
    float* h1           = (float*)((char*)d_ws + WS_H1_OFF);
    unsigned char* q2   = (unsigned char*)((char*)d_ws + WS_Q2_OFF);
    float* o2           = (float*)((char*)d_ws + WS_O2_OFF);
    unsigned int* S1    = (unsigned int*)(F + 520);
    unsigned int* S2    = (unsigned int*)(F + 620);

    hipMemsetAsync(d_ws, 0, 4096, stream);
    k_absmax <<<2065, 256, 0, stream>>>(sig, W1, W2, F);
    k_prep   <<<1010, 256, 0, stream>>>(W1, b1, W2, F, w1q);
    k_gemm1  <<<512,  256, 0, stream>>>(sig, w1q, F, h1);
    k_quant_h<<<256,  256, 0, stream>>>(h1, q2, F, S1, S2);
    k_bnprep <<<1,    128, 0, stream>>>(b2, F, S1, S2);
    k_gemm2  <<<64,   256, 0, stream>>>(q2, F, gamma, beta, o2);
    k_final  <<<32,   256, 0, stream>>>(o2, F, (float*)d_out);
}